// Round 11
// baseline (1032.353 us; speedup 1.0000x reference)
//
#include <hip/hip_runtime.h>
#include <hip/hip_fp16.h>
#include <hip/hip_cooperative_groups.h>

namespace cg = cooperative_groups;

typedef float fx2 __attribute__((ext_vector_type(2)));
typedef float fx4 __attribute__((ext_vector_type(4)));

constexpr int   N       = 8192;
constexpr float INV_REG = 10.0f;    // 1/REG
constexpr float THRESH  = 1e-3f;
constexpr float EPSV    = 1e-8f;
constexpr int   MAX_IT  = 100;
constexpr int   NTHR    = 256;      // block size for non-loop kernels
constexpr int   LTHR    = 1024;     // loop block size (16 waves)
constexpr int   LBLK    = 256;      // loop grid: 1 block per CU

// ---------------- fp8 e4m3 (OCP) helpers ----------------------------------
#if defined(__HIP_DEVICE_COMPILE__) && __has_builtin(__builtin_amdgcn_cvt_pk_f32_fp8) && __has_builtin(__builtin_amdgcn_cvt_pk_fp8_f32)
#define FP8_HW 1
#else
#define FP8_HW 0
#endif

template <bool HI>
__device__ __forceinline__ fx2 fp8x2_dec(unsigned int w)
{
#if FP8_HW
    return __builtin_amdgcn_cvt_pk_f32_fp8((int)w, HI);
#else
    unsigned int s = HI ? (w >> 16) : (w & 0xFFFFu);
    unsigned int b0 = s & 0xFFu, b1 = (s >> 8) & 0xFFu;
    unsigned int e0 = (b0 >> 3) & 0xFu, m0 = b0 & 7u;
    unsigned int e1 = (b1 >> 3) & 0xFu, m1 = b1 & 7u;
    fx2 r;
    r.x = e0 ? __builtin_bit_cast(float, ((e0 + 120u) << 23) | (m0 << 20))
             : (float)m0 * 0.001953125f;
    r.y = e1 ? __builtin_bit_cast(float, ((e1 + 120u) << 23) | (m1 << 20))
             : (float)m1 * 0.001953125f;
    return r;
#endif
}

__device__ __forceinline__ unsigned int fp8_enc1(float x)
{
    if (x < 0.015625f) return (unsigned int)(int)rintf(x * 512.0f);
    unsigned int bits = __builtin_bit_cast(unsigned int, x);
    unsigned int e = bits >> 23;
    unsigned int m = bits & 0x7FFFFFu;
    m += 0x7FFFFu + ((m >> 20) & 1u);
    if (m >> 23) { m = 0; e += 1; }
    return ((e - 120u) << 3) | (m >> 20);
}

__device__ __forceinline__ unsigned int fp8x4_enc(float a, float b, float c, float d)
{
#if FP8_HW
    int w = __builtin_amdgcn_cvt_pk_fp8_f32(a, b, 0, false);
    w     = __builtin_amdgcn_cvt_pk_fp8_f32(c, d, w, true);
    return (unsigned int)w;
#else
    return fp8_enc1(a) | (fp8_enc1(b) << 8) | (fp8_enc1(c) << 16) | (fp8_enc1(d) << 24);
#endif
}

__device__ __forceinline__ float2 h2f2(unsigned int h)
{
    return __half22float2(*reinterpret_cast<const __half2*>(&h));
}

__device__ __forceinline__ float wave_sum(float x)
{
    #pragma unroll
    for (int off = 32; off > 0; off >>= 1) x += __shfl_down(x, off, 64);
    return x;  // lane 0 holds the sum
}

// full-row fp8 dot: pre-issue ALL 8 row loads (128 B/lane in flight), then
// consume against LDS-staged fp16 vector.
__device__ __forceinline__ float dot_fp8_row(const unsigned char* __restrict__ row,
                                             const __half* __restrict__ sv, int lane)
{
    const uint4* r4 = (const uint4*)row;   // 512 x 16 fp8
    const uint4* s4 = (const uint4*)sv;    // 1024 x 8 halves
    uint4 kk[8];
    #pragma unroll
    for (int t = 0; t < 8; ++t) kk[t] = r4[lane + 64 * t];

    float a0 = 0.f, a1 = 0.f, a2 = 0.f, a3 = 0.f;
    #pragma unroll
    for (int t = 0; t < 8; ++t) {
        const int c = lane + 64 * t;
        uint4 h0 = s4[2 * c];
        uint4 h1 = s4[2 * c + 1];
        fx2 f; float2 g;
        f = fp8x2_dec<false>(kk[t].x); g = h2f2(h0.x); a0 += f.x * g.x; a1 += f.y * g.y;
        f = fp8x2_dec<true >(kk[t].x); g = h2f2(h0.y); a2 += f.x * g.x; a3 += f.y * g.y;
        f = fp8x2_dec<false>(kk[t].y); g = h2f2(h0.z); a0 += f.x * g.x; a1 += f.y * g.y;
        f = fp8x2_dec<true >(kk[t].y); g = h2f2(h0.w); a2 += f.x * g.x; a3 += f.y * g.y;
        f = fp8x2_dec<false>(kk[t].z); g = h2f2(h1.x); a0 += f.x * g.x; a1 += f.y * g.y;
        f = fp8x2_dec<true >(kk[t].z); g = h2f2(h1.y); a2 += f.x * g.x; a3 += f.y * g.y;
        f = fp8x2_dec<false>(kk[t].w); g = h2f2(h1.z); a0 += f.x * g.x; a1 += f.y * g.y;
        f = fp8x2_dec<true >(kk[t].w); g = h2f2(h1.w); a2 += f.x * g.x; a3 += f.y * g.y;
    }
    return (a0 + a1) + (a2 + a3);
}

// ===========================================================================
// init: K8 = fp8(exp(-cost/REG)) row-major AND KT8 = fp8 transposed, via
// 128x128 byte LDS tile. u32/u16 = 1/N. grid = (64,64) x 256.
// ===========================================================================
__global__ __launch_bounds__(NTHR)
void k_init8(const float* __restrict__ cost, unsigned char* __restrict__ K8,
             unsigned char* __restrict__ KT8, float* __restrict__ u32,
             __half* __restrict__ u16)
{
    __shared__ unsigned char tile[128][132];   // +4 pad
    const int r0 = blockIdx.y << 7;
    const int c0 = blockIdx.x << 7;
    const int tx = threadIdx.x & 31;    // 32 x 4 cols = 128
    const int ty = threadIdx.x >> 5;    // 8 rows / pass

    for (int p = 0; p < 16; ++p) {
        const int r = p * 8 + ty;
        fx4 c = __builtin_nontemporal_load(
            (const fx4*)(cost + (size_t)(r0 + r) * N + c0) + tx);
        unsigned int enc = fp8x4_enc(__expf(-INV_REG * c.x), __expf(-INV_REG * c.y),
                                     __expf(-INV_REG * c.z), __expf(-INV_REG * c.w));
        ((unsigned int*)(K8 + (size_t)(r0 + r) * N + c0))[tx] = enc;
        *(unsigned int*)&tile[r][tx * 4] = enc;
    }
    __syncthreads();

    for (int p = 0; p < 16; ++p) {
        const int c = p * 8 + ty;       // tile col == KT8 row
        unsigned int w = (unsigned int)tile[tx * 4 + 0][c]
                       | ((unsigned int)tile[tx * 4 + 1][c] << 8)
                       | ((unsigned int)tile[tx * 4 + 2][c] << 16)
                       | ((unsigned int)tile[tx * 4 + 3][c] << 24);
        ((unsigned int*)(KT8 + (size_t)(c0 + c) * N + r0))[tx] = w;
    }

    if (blockIdx.y == 0 && blockIdx.x < 32) {
        const int g = blockIdx.x * NTHR + threadIdx.x;
        u32[g] = 1.0f / (float)N;
        u16[g] = __float2half(1.0f / (float)N);   // 2^-13, exact in fp16
    }
}

// ===========================================================================
// cooperative loop: 256 blocks x 1024 threads (1 block/CU, 16 waves/CU).
// 2 grid.syncs/iter. Per phase each wave handles 2 rows.
//   A: v[j] = b[j]/(KT8[j,:].u16 + eps)
//   B: u[i] = a[i]/(K8 [i,:].v16 + eps); block-partial d^2 -> bsum[bid]
//   C: all blocks reduce bsum[0..255] in identical order -> same exit bit
// ===========================================================================
__global__ __launch_bounds__(LTHR, 1)
void sinkhorn_loop8(const float* __restrict__ av, const float* __restrict__ bv,
                    float* __restrict__ u32, float* __restrict__ v32,
                    __half* __restrict__ u16, __half* __restrict__ v16,
                    float* __restrict__ bsum,
                    const unsigned char* __restrict__ K8,
                    const unsigned char* __restrict__ KT8)
{
    cg::grid_group grid = cg::this_grid();

    const int tid  = threadIdx.x;
    const int bid  = blockIdx.x;
    const int nblk = gridDim.x;               // 256
    const int rpb  = N / nblk;                // 32 rows/block
    const int nw   = LTHR / 64;               // 16 waves
    const int pw   = rpb / nw;                // 2 rows/wave
    const int w    = tid >> 6;
    const int lane = tid & 63;

    __shared__ __align__(16) __half stage[N];   // 16 KB
    __shared__ float red[16];
    __shared__ float err_sh;

    int iter = 0;
    while (true) {
        // ---- A: v-update over KT8 rows ----
        {
            const int j4 = tid;                  // exactly N/8 = 1024 uint4
            ((uint4*)stage)[j4] = ((const uint4*)u16)[j4];
        }
        __syncthreads();
        for (int rr = 0; rr < pw; ++rr) {
            const int j = bid * rpb + w * pw + rr;
            float acc = dot_fp8_row(KT8 + (size_t)j * N, stage, lane);
            acc = wave_sum(acc);
            if (lane == 0) {
                float vn = bv[j] / (acc + EPSV);
                v32[j] = vn;
                v16[j] = __float2half(vn);
            }
        }
        grid.sync();

        // ---- B: u-update over K8 rows + block-partial d^2 ----
        {
            const int j4 = tid;
            ((uint4*)stage)[j4] = ((const uint4*)v16)[j4];
        }
        __syncthreads();
        float mydu = 0.f;
        for (int rr = 0; rr < pw; ++rr) {
            const int i = bid * rpb + w * pw + rr;
            float acc = dot_fp8_row(K8 + (size_t)i * N, stage, lane);
            acc = wave_sum(acc);
            if (lane == 0) {
                float un = av[i] / (acc + EPSV);
                float d  = un - u32[i];
                mydu += d * d;
                u32[i] = un;
                u16[i] = __float2half(un);
            }
        }
        if (lane == 0) red[w] = mydu;
        __syncthreads();
        if (tid == 0) {
            float s = 0.f;
            #pragma unroll
            for (int t = 0; t < 16; ++t) s += red[t];
            bsum[bid] = s;
        }
        grid.sync();

        // ---- C: every block reduces bsum[0..nblk) identically ----
        {
            float s = (tid < nblk) ? bsum[tid] : 0.f;
            s = wave_sum(s);
            if (lane == 0) red[w] = s;
            __syncthreads();
            if (tid == 0) {
                float t0 = 0.f;
                #pragma unroll
                for (int t = 0; t < 16; ++t) t0 += red[t];
                err_sh = sqrtf(t0);
            }
            __syncthreads();
            float err = err_sh;
            ++iter;
            if (iter >= MAX_IT || err < THRESH) break;
        }
        // C->A: A reads u16 (grid-synced after B); stage reuse is block-local.
    }
}

// ===========================================================================
// output: out[i][j] = u_i * exp(-cost_ij/REG) * v_j (exact fp32 K recompute)
// ===========================================================================
__global__ __launch_bounds__(NTHR)
void k_output(const float* __restrict__ cost, const float* __restrict__ u,
              const float* __restrict__ v, float* __restrict__ out)
{
    __shared__ __align__(16) float vl[N];
    for (int j = threadIdx.x; j < N / 4; j += NTHR)
        ((float4*)vl)[j] = ((const float4*)v)[j];
    __syncthreads();

    const int w    = threadIdx.x >> 6;
    const int lane = threadIdx.x & 63;
    const int i    = blockIdx.x * 4 + w;
    const float ui = u[i];
    const fx4* crow = (const fx4*)(cost + (size_t)i * N);
    fx4*       orow = (fx4*)(out + (size_t)i * N);
    #pragma unroll 4
    for (int c = lane; c < N / 4; c += 64) {
        fx4 cc = __builtin_nontemporal_load(&crow[c]);
        float4 vv = ((const float4*)vl)[c];
        fx4 o;
        o.x = ui * __expf(-INV_REG * cc.x) * vv.x;
        o.y = ui * __expf(-INV_REG * cc.y) * vv.y;
        o.z = ui * __expf(-INV_REG * cc.z) * vv.z;
        o.w = ui * __expf(-INV_REG * cc.w) * vv.w;
        __builtin_nontemporal_store(o, &orow[c]);
    }
}

// ===========================================================================
// Tier-3 fallback (round-2 proven multi-kernel, fp32 K in d_out)
// ===========================================================================
constexpr int NSLAB_F = 64;

__global__ __launch_bounds__(256)
void k_init(const float* __restrict__ cost, float* __restrict__ K,
            float* __restrict__ u, int* __restrict__ flag)
{
    const int gtid = blockIdx.x * 256 + threadIdx.x;
    const int gsz  = gridDim.x * 256;
    const float4* c4 = (const float4*)cost;
    float4*       k4 = (float4*)K;
    const int tot4 = N * N / 4;
    for (int i = gtid; i < tot4; i += gsz) {
        float4 c = c4[i];
        float4 k;
        k.x = __expf(-INV_REG * c.x);
        k.y = __expf(-INV_REG * c.y);
        k.z = __expf(-INV_REG * c.z);
        k.w = __expf(-INV_REG * c.w);
        k4[i] = k;
    }
    if (gtid < N) u[gtid] = 1.0f / (float)N;
    if (gtid == 0) *flag = 0;
}

__global__ __launch_bounds__(256)
void k_colmv(const float* __restrict__ K, const float* __restrict__ u,
             float* __restrict__ partial, const int* __restrict__ flag)
{
    if (*flag) return;
    __shared__ float  uh[128];
    __shared__ __align__(16) float4 accs[128];
    const int rs = blockIdx.x >> 4;
    const int cs = blockIdx.x & 15;
    const int r0 = rs * 128;
    const int c0 = cs * 512;
    const int l  = threadIdx.x & 127;
    const int h  = threadIdx.x >> 7;
    if (threadIdx.x < 128) uh[threadIdx.x] = u[r0 + threadIdx.x];
    __syncthreads();
    float4 acc = make_float4(0.f, 0.f, 0.f, 0.f);
    for (int r = h; r < 128; r += 2) {
        float4 k = ((const float4*)(K + (size_t)(r0 + r) * N))[(c0 >> 2) + l];
        float uu = uh[r];
        acc.x += k.x * uu; acc.y += k.y * uu; acc.z += k.z * uu; acc.w += k.w * uu;
    }
    if (h == 1) accs[l] = acc;
    __syncthreads();
    if (h == 0) {
        float4 o = accs[l];
        acc.x += o.x; acc.y += o.y; acc.z += o.z; acc.w += o.w;
        ((float4*)(partial + (size_t)rs * N + c0))[l] = acc;
    }
}

__global__ __launch_bounds__(256)
void k_v(const float* __restrict__ partial, const float* __restrict__ bv,
         float* __restrict__ v, const int* __restrict__ flag)
{
    if (*flag) return;
    const int j = blockIdx.x * 256 + threadIdx.x;
    float s = 0.f;
    for (int sl = 0; sl < NSLAB_F; ++sl) s += partial[(size_t)sl * N + j];
    v[j] = bv[j] / (s + EPSV);
}

__global__ __launch_bounds__(256)
void k_rowmv(const float* __restrict__ K, const float* __restrict__ av,
             const float* __restrict__ v, float* __restrict__ u,
             float* __restrict__ du2, const int* __restrict__ flag)
{
    if (*flag) return;
    __shared__ __align__(16) float vl[N];
    for (int j = threadIdx.x; j < N / 4; j += 256)
        ((float4*)vl)[j] = ((const float4*)v)[j];
    __syncthreads();
    const int w    = threadIdx.x >> 6;
    const int lane = threadIdx.x & 63;
    const int i    = blockIdx.x * 4 + w;
    const float4* krow = (const float4*)(K + (size_t)i * N);
    const float4* v4   = (const float4*)vl;
    float acc = 0.f;
    for (int c = lane; c < N / 4; c += 64) {
        float4 k  = krow[c];
        float4 vv = v4[c];
        acc += k.x * vv.x + k.y * vv.y + k.z * vv.z + k.w * vv.w;
    }
    for (int off = 32; off > 0; off >>= 1)
        acc += __shfl_down(acc, off, 64);
    if (lane == 0) {
        float un = av[i] / (acc + EPSV);
        float d  = un - u[i];
        du2[i] = d * d;
        u[i]   = un;
    }
}

__global__ __launch_bounds__(256)
void k_err(const float* __restrict__ du2, int* __restrict__ flag)
{
    if (*flag) return;
    __shared__ float r[4];
    float s = 0.f;
    for (int i = threadIdx.x; i < N; i += 256) s += du2[i];
    for (int off = 32; off > 0; off >>= 1)
        s += __shfl_down(s, off, 64);
    if ((threadIdx.x & 63) == 0) r[threadIdx.x >> 6] = s;
    __syncthreads();
    if (threadIdx.x == 0) {
        float e = sqrtf(r[0] + r[1] + r[2] + r[3]);
        if (e < THRESH) *flag = 1;
    }
}

__global__ __launch_bounds__(256)
void k_final(float* __restrict__ K, const float* __restrict__ u,
             const float* __restrict__ v)
{
    __shared__ __align__(16) float vl[N];
    for (int j = threadIdx.x; j < N / 4; j += 256)
        ((float4*)vl)[j] = ((const float4*)v)[j];
    __syncthreads();
    const int w    = threadIdx.x >> 6;
    const int lane = threadIdx.x & 63;
    const int i    = blockIdx.x * 4 + w;
    const float ui = u[i];
    float4* krow = (float4*)(K + (size_t)i * N);
    const float4* v4 = (const float4*)vl;
    for (int c = lane; c < N / 4; c += 64) {
        float4 k  = krow[c];
        float4 vv = v4[c];
        k.x *= ui * vv.x; k.y *= ui * vv.y; k.z *= ui * vv.z; k.w *= ui * vv.w;
        krow[c] = k;
    }
}

// ===========================================================================
extern "C" void kernel_launch(void* const* d_in, const int* in_sizes, int n_in,
                              void* d_out, int out_size, void* d_ws, size_t ws_size,
                              hipStream_t stream)
{
    const float* cost = (const float*)d_in[0];
    const float* av   = (const float*)d_in[1];
    const float* bv   = (const float*)d_in[2];
    float* out = (float*)d_out;

    // ws layout: u32[N] | v32[N] | bsum[2048] | u16[N] | v16[N] | K8 | KT8
    float*  u32  = (float*)d_ws;
    float*  v32  = u32 + N;
    float*  bsum = v32 + N;
    __half* u16  = (__half*)(bsum + 2048);
    __half* v16  = u16 + N;
    unsigned char* base = (unsigned char*)(v16 + N);   // byte offset 106496
    const size_t szK8  = (size_t)N * N;
    const size_t need8 = (size_t)106496 + 2 * szK8;    // ~128 MB

    if (ws_size >= need8) {
        int maxb = 0;
        (void)hipOccupancyMaxActiveBlocksPerMultiprocessor(
            &maxb, (const void*)sinkhorn_loop8, LTHR, 0);
        if (maxb >= 1) {
            unsigned char* K8  = base;
            unsigned char* KT8 = base + szK8;
            k_init8<<<dim3(64, 64), NTHR, 0, stream>>>(cost, K8, KT8, u32, u16);
            void* args[] = { (void*)&av, (void*)&bv, (void*)&u32, (void*)&v32,
                             (void*)&u16, (void*)&v16, (void*)&bsum,
                             (void*)&K8, (void*)&KT8 };
            hipError_t rc = hipLaunchCooperativeKernel(
                (const void*)sinkhorn_loop8, dim3(LBLK), dim3(LTHR),
                args, 0, stream);
            if (rc == hipSuccess) {
                k_output<<<2048, NTHR, 0, stream>>>(cost, u32, v32, out);
                return;
            }
        }
    }

    // ---- tier 3: proven multi-kernel fp32 path ----
    int*   flag    = (int*)d_ws;
    float* uf      = (float*)d_ws + 16;
    float* vf      = uf + N;
    float* du2f    = vf + N;
    float* partial = du2f + N;

    k_init<<<2048, 256, 0, stream>>>(cost, out, uf, flag);
    for (int it = 0; it < MAX_IT; ++it) {
        k_colmv<<<1024, 256, 0, stream>>>(out, uf, partial, flag);
        k_v    <<<  32, 256, 0, stream>>>(partial, bv, vf, flag);
        k_rowmv<<<2048, 256, 0, stream>>>(out, av, vf, uf, du2f, flag);
        k_err  <<<   1, 256, 0, stream>>>(du2f, flag);
    }
    k_final<<<2048, 256, 0, stream>>>(out, uf, vf);
}

// Round 12
// 617.254 us; speedup vs baseline: 1.6725x; 1.6725x over previous
//
#include <hip/hip_runtime.h>
#include <hip/hip_fp16.h>

typedef float fx2 __attribute__((ext_vector_type(2)));
typedef float fx4 __attribute__((ext_vector_type(4)));

constexpr int   N       = 8192;
constexpr float INV_REG = 10.0f;    // 1/REG
constexpr float THRESH  = 1e-3f;
constexpr float EPSV    = 1e-8f;
constexpr int   MAX_IT  = 100;
constexpr int   NTHR    = 256;      // block size for init/output kernels
constexpr int   LTHR    = 1024;     // loop block size (16 waves)
constexpr int   LBLK    = 256;      // loop grid; capacity 2/CU -> always resident

// ---------------- fp8 e4m3 (OCP) helpers ----------------------------------
#if defined(__HIP_DEVICE_COMPILE__) && __has_builtin(__builtin_amdgcn_cvt_pk_f32_fp8) && __has_builtin(__builtin_amdgcn_cvt_pk_fp8_f32)
#define FP8_HW 1
#else
#define FP8_HW 0
#endif

template <bool HI>
__device__ __forceinline__ fx2 fp8x2_dec(unsigned int w)
{
#if FP8_HW
    return __builtin_amdgcn_cvt_pk_f32_fp8((int)w, HI);
#else
    unsigned int s = HI ? (w >> 16) : (w & 0xFFFFu);
    unsigned int b0 = s & 0xFFu, b1 = (s >> 8) & 0xFFu;
    unsigned int e0 = (b0 >> 3) & 0xFu, m0 = b0 & 7u;
    unsigned int e1 = (b1 >> 3) & 0xFu, m1 = b1 & 7u;
    fx2 r;
    r.x = e0 ? __builtin_bit_cast(float, ((e0 + 120u) << 23) | (m0 << 20))
             : (float)m0 * 0.001953125f;
    r.y = e1 ? __builtin_bit_cast(float, ((e1 + 120u) << 23) | (m1 << 20))
             : (float)m1 * 0.001953125f;
    return r;
#endif
}

__device__ __forceinline__ unsigned int fp8_enc1(float x)
{
    if (x < 0.015625f) return (unsigned int)(int)rintf(x * 512.0f);
    unsigned int bits = __builtin_bit_cast(unsigned int, x);
    unsigned int e = bits >> 23;
    unsigned int m = bits & 0x7FFFFFu;
    m += 0x7FFFFu + ((m >> 20) & 1u);
    if (m >> 23) { m = 0; e += 1; }
    return ((e - 120u) << 3) | (m >> 20);
}

__device__ __forceinline__ unsigned int fp8x4_enc(float a, float b, float c, float d)
{
#if FP8_HW
    int w = __builtin_amdgcn_cvt_pk_fp8_f32(a, b, 0, false);
    w     = __builtin_amdgcn_cvt_pk_fp8_f32(c, d, w, true);
    return (unsigned int)w;
#else
    return fp8_enc1(a) | (fp8_enc1(b) << 8) | (fp8_enc1(c) << 16) | (fp8_enc1(d) << 24);
#endif
}

__device__ __forceinline__ float2 h2f2(unsigned int h)
{
    return __half22float2(*reinterpret_cast<const __half2*>(&h));
}

__device__ __forceinline__ float wave_sum(float x)
{
    #pragma unroll
    for (int off = 32; off > 0; off >>= 1) x += __shfl_down(x, off, 64);
    return x;  // lane 0 holds the sum
}

// Manual grid barrier: monotonic device-scope counter. The AGENT-scope
// release on arrive writes back the XCD-local L2; the AGENT-scope acquire
// on the poll invalidates stale lines (cross-XCD coherence, G16).
__device__ __forceinline__ void grid_barrier(unsigned int* bar, unsigned int target)
{
    __syncthreads();                 // all block mem-ops drained (vmcnt 0)
    if (threadIdx.x == 0) {
        __hip_atomic_fetch_add(bar, 1u, __ATOMIC_ACQ_REL, __HIP_MEMORY_SCOPE_AGENT);
        while (__hip_atomic_load(bar, __ATOMIC_ACQUIRE, __HIP_MEMORY_SCOPE_AGENT) < target)
            __builtin_amdgcn_s_sleep(2);
    }
    __syncthreads();
}

// full-row fp8 dot: pre-issue ALL 8 row loads (128 B/lane in flight), then
// consume against LDS-staged fp16 vector.
__device__ __forceinline__ float dot_fp8_row(const unsigned char* __restrict__ row,
                                             const __half* __restrict__ sv, int lane)
{
    const uint4* r4 = (const uint4*)row;   // 512 x 16 fp8
    const uint4* s4 = (const uint4*)sv;    // 1024 x 8 halves
    uint4 kk[8];
    #pragma unroll
    for (int t = 0; t < 8; ++t) kk[t] = r4[lane + 64 * t];

    float a0 = 0.f, a1 = 0.f, a2 = 0.f, a3 = 0.f;
    #pragma unroll
    for (int t = 0; t < 8; ++t) {
        const int c = lane + 64 * t;
        uint4 h0 = s4[2 * c];
        uint4 h1 = s4[2 * c + 1];
        fx2 f; float2 g;
        f = fp8x2_dec<false>(kk[t].x); g = h2f2(h0.x); a0 += f.x * g.x; a1 += f.y * g.y;
        f = fp8x2_dec<true >(kk[t].x); g = h2f2(h0.y); a2 += f.x * g.x; a3 += f.y * g.y;
        f = fp8x2_dec<false>(kk[t].y); g = h2f2(h0.z); a0 += f.x * g.x; a1 += f.y * g.y;
        f = fp8x2_dec<true >(kk[t].y); g = h2f2(h0.w); a2 += f.x * g.x; a3 += f.y * g.y;
        f = fp8x2_dec<false>(kk[t].z); g = h2f2(h1.x); a0 += f.x * g.x; a1 += f.y * g.y;
        f = fp8x2_dec<true >(kk[t].z); g = h2f2(h1.y); a2 += f.x * g.x; a3 += f.y * g.y;
        f = fp8x2_dec<false>(kk[t].w); g = h2f2(h1.z); a0 += f.x * g.x; a1 += f.y * g.y;
        f = fp8x2_dec<true >(kk[t].w); g = h2f2(h1.w); a2 += f.x * g.x; a3 += f.y * g.y;
    }
    return (a0 + a1) + (a2 + a3);
}

// ===========================================================================
// init: K8 = fp8(exp(-cost/REG)) row-major AND KT8 = fp8 transposed, via
// 128x128 byte LDS tile. u32/u16 = 1/N; barrier counter = 0 (every replay).
// grid = (64,64) x 256.
// ===========================================================================
__global__ __launch_bounds__(NTHR)
void k_init8(const float* __restrict__ cost, unsigned char* __restrict__ K8,
             unsigned char* __restrict__ KT8, float* __restrict__ u32,
             __half* __restrict__ u16, unsigned int* __restrict__ bar)
{
    __shared__ unsigned char tile[128][132];   // +4 pad
    const int r0 = blockIdx.y << 7;
    const int c0 = blockIdx.x << 7;
    const int tx = threadIdx.x & 31;    // 32 x 4 cols = 128
    const int ty = threadIdx.x >> 5;    // 8 rows / pass

    for (int p = 0; p < 16; ++p) {
        const int r = p * 8 + ty;
        fx4 c = __builtin_nontemporal_load(
            (const fx4*)(cost + (size_t)(r0 + r) * N + c0) + tx);
        unsigned int enc = fp8x4_enc(__expf(-INV_REG * c.x), __expf(-INV_REG * c.y),
                                     __expf(-INV_REG * c.z), __expf(-INV_REG * c.w));
        ((unsigned int*)(K8 + (size_t)(r0 + r) * N + c0))[tx] = enc;
        *(unsigned int*)&tile[r][tx * 4] = enc;
    }
    __syncthreads();

    for (int p = 0; p < 16; ++p) {
        const int c = p * 8 + ty;       // tile col == KT8 row
        unsigned int w = (unsigned int)tile[tx * 4 + 0][c]
                       | ((unsigned int)tile[tx * 4 + 1][c] << 8)
                       | ((unsigned int)tile[tx * 4 + 2][c] << 16)
                       | ((unsigned int)tile[tx * 4 + 3][c] << 24);
        ((unsigned int*)(KT8 + (size_t)(c0 + c) * N + r0))[tx] = w;
    }

    if (blockIdx.y == 0 && blockIdx.x < 32) {
        const int g = blockIdx.x * NTHR + threadIdx.x;
        u32[g] = 1.0f / (float)N;
        u16[g] = __float2half(1.0f / (float)N);   // 2^-13, exact in fp16
    }
    if (blockIdx.x == 0 && blockIdx.y == 0 && threadIdx.x == 0)
        __hip_atomic_store(bar, 0u, __ATOMIC_RELEASE, __HIP_MEMORY_SCOPE_AGENT);
}

// ===========================================================================
// loop: PLAIN launch, 256 blocks x 1024 threads, manual grid barrier.
// 2 barriers/iter. Per phase each wave handles 2 rows.
//   A: v[j] = b[j]/(KT8[j,:].u16 + eps)
//   B: u[i] = a[i]/(K8 [i,:].v16 + eps); block-partial d^2 -> bsum[bid]
//   C: all blocks reduce bsum[0..255] in identical order -> same exit bit
// __launch_bounds__(1024, 8): forces VGPR<=64 -> 2 blocks/CU capacity ->
// all 256 blocks resident under any dispatch skew (>=128 CUs suffice).
// ===========================================================================
__global__ __launch_bounds__(LTHR, 8)
void sinkhorn_loop8(const float* __restrict__ av, const float* __restrict__ bv,
                    float* __restrict__ u32, float* __restrict__ v32,
                    __half* __restrict__ u16, __half* __restrict__ v16,
                    float* __restrict__ bsum, unsigned int* __restrict__ bar,
                    const unsigned char* __restrict__ K8,
                    const unsigned char* __restrict__ KT8)
{
    const int tid  = threadIdx.x;
    const int bid  = blockIdx.x;
    const int nblk = gridDim.x;               // 256
    const int rpb  = N / nblk;                // 32 rows/block
    const int nw   = LTHR / 64;               // 16 waves
    const int pw   = rpb / nw;                // 2 rows/wave
    const int w    = tid >> 6;
    const int lane = tid & 63;

    __shared__ __align__(16) __half stage[N];   // 16 KB
    __shared__ float red[16];
    __shared__ float err_sh;

    unsigned int gen = 0;
    int iter = 0;
    while (true) {
        // ---- A: v-update over KT8 rows ----
        ((uint4*)stage)[tid] = ((const uint4*)u16)[tid];   // N/8 == LTHR
        __syncthreads();
        for (int rr = 0; rr < pw; ++rr) {
            const int j = bid * rpb + w * pw + rr;
            float acc = dot_fp8_row(KT8 + (size_t)j * N, stage, lane);
            acc = wave_sum(acc);
            if (lane == 0) {
                float vn = bv[j] / (acc + EPSV);
                v32[j] = vn;
                v16[j] = __float2half(vn);
            }
        }
        ++gen;
        grid_barrier(bar, (unsigned int)nblk * gen);

        // ---- B: u-update over K8 rows + block-partial d^2 ----
        ((uint4*)stage)[tid] = ((const uint4*)v16)[tid];
        __syncthreads();
        float mydu = 0.f;
        for (int rr = 0; rr < pw; ++rr) {
            const int i = bid * rpb + w * pw + rr;
            float acc = dot_fp8_row(K8 + (size_t)i * N, stage, lane);
            acc = wave_sum(acc);
            if (lane == 0) {
                float un = av[i] / (acc + EPSV);
                float d  = un - u32[i];
                mydu += d * d;
                u32[i] = un;
                u16[i] = __float2half(un);
            }
        }
        if (lane == 0) red[w] = mydu;
        __syncthreads();
        if (tid == 0) {
            float s = 0.f;
            #pragma unroll
            for (int t = 0; t < 16; ++t) s += red[t];
            bsum[bid] = s;
        }
        ++gen;
        grid_barrier(bar, (unsigned int)nblk * gen);

        // ---- C: every block reduces bsum[0..nblk) identically ----
        {
            float s = (tid < nblk) ? bsum[tid] : 0.f;
            s = wave_sum(s);
            if (lane == 0) red[w] = s;
            __syncthreads();
            if (tid == 0) {
                float t0 = 0.f;
                #pragma unroll
                for (int t = 0; t < 16; ++t) t0 += red[t];
                err_sh = sqrtf(t0);
            }
            __syncthreads();
            float err = err_sh;
            ++iter;
            if (iter >= MAX_IT || err < THRESH) break;
        }
        // C->A safe: next B's bsum writes happen only after barrier #1, which
        // requires every block to have finished its C-phase bsum reads.
    }
}

// ===========================================================================
// output: out[i][j] = u_i * exp(-cost_ij/REG) * v_j (exact fp32 K recompute)
// ===========================================================================
__global__ __launch_bounds__(NTHR)
void k_output(const float* __restrict__ cost, const float* __restrict__ u,
              const float* __restrict__ v, float* __restrict__ out)
{
    __shared__ __align__(16) float vl[N];
    for (int j = threadIdx.x; j < N / 4; j += NTHR)
        ((float4*)vl)[j] = ((const float4*)v)[j];
    __syncthreads();

    const int w    = threadIdx.x >> 6;
    const int lane = threadIdx.x & 63;
    const int i    = blockIdx.x * 4 + w;
    const float ui = u[i];
    const fx4* crow = (const fx4*)(cost + (size_t)i * N);
    fx4*       orow = (fx4*)(out + (size_t)i * N);
    #pragma unroll 4
    for (int c = lane; c < N / 4; c += 64) {
        fx4 cc = __builtin_nontemporal_load(&crow[c]);
        float4 vv = ((const float4*)vl)[c];
        fx4 o;
        o.x = ui * __expf(-INV_REG * cc.x) * vv.x;
        o.y = ui * __expf(-INV_REG * cc.y) * vv.y;
        o.z = ui * __expf(-INV_REG * cc.z) * vv.z;
        o.w = ui * __expf(-INV_REG * cc.w) * vv.w;
        __builtin_nontemporal_store(o, &orow[c]);
    }
}

// ===========================================================================
// Tier-3 fallback (round-2 proven multi-kernel, fp32 K in d_out) — only if
// ws_size can't hold the fp8 shadows (never observed; ws >= 192 MB).
// ===========================================================================
constexpr int NSLAB_F = 64;

__global__ __launch_bounds__(256)
void k_init(const float* __restrict__ cost, float* __restrict__ K,
            float* __restrict__ u, int* __restrict__ flag)
{
    const int gtid = blockIdx.x * 256 + threadIdx.x;
    const int gsz  = gridDim.x * 256;
    const float4* c4 = (const float4*)cost;
    float4*       k4 = (float4*)K;
    const int tot4 = N * N / 4;
    for (int i = gtid; i < tot4; i += gsz) {
        float4 c = c4[i];
        float4 k;
        k.x = __expf(-INV_REG * c.x);
        k.y = __expf(-INV_REG * c.y);
        k.z = __expf(-INV_REG * c.z);
        k.w = __expf(-INV_REG * c.w);
        k4[i] = k;
    }
    if (gtid < N) u[gtid] = 1.0f / (float)N;
    if (gtid == 0) *flag = 0;
}

__global__ __launch_bounds__(256)
void k_colmv(const float* __restrict__ K, const float* __restrict__ u,
             float* __restrict__ partial, const int* __restrict__ flag)
{
    if (*flag) return;
    __shared__ float  uh[128];
    __shared__ __align__(16) float4 accs[128];
    const int rs = blockIdx.x >> 4;
    const int cs = blockIdx.x & 15;
    const int r0 = rs * 128;
    const int c0 = cs * 512;
    const int l  = threadIdx.x & 127;
    const int h  = threadIdx.x >> 7;
    if (threadIdx.x < 128) uh[threadIdx.x] = u[r0 + threadIdx.x];
    __syncthreads();
    float4 acc = make_float4(0.f, 0.f, 0.f, 0.f);
    for (int r = h; r < 128; r += 2) {
        float4 k = ((const float4*)(K + (size_t)(r0 + r) * N))[(c0 >> 2) + l];
        float uu = uh[r];
        acc.x += k.x * uu; acc.y += k.y * uu; acc.z += k.z * uu; acc.w += k.w * uu;
    }
    if (h == 1) accs[l] = acc;
    __syncthreads();
    if (h == 0) {
        float4 o = accs[l];
        acc.x += o.x; acc.y += o.y; acc.z += o.z; acc.w += o.w;
        ((float4*)(partial + (size_t)rs * N + c0))[l] = acc;
    }
}

__global__ __launch_bounds__(256)
void k_v(const float* __restrict__ partial, const float* __restrict__ bv,
         float* __restrict__ v, const int* __restrict__ flag)
{
    if (*flag) return;
    const int j = blockIdx.x * 256 + threadIdx.x;
    float s = 0.f;
    for (int sl = 0; sl < NSLAB_F; ++sl) s += partial[(size_t)sl * N + j];
    v[j] = bv[j] / (s + EPSV);
}

__global__ __launch_bounds__(256)
void k_rowmv(const float* __restrict__ K, const float* __restrict__ av,
             const float* __restrict__ v, float* __restrict__ u,
             float* __restrict__ du2, const int* __restrict__ flag)
{
    if (*flag) return;
    __shared__ __align__(16) float vl[N];
    for (int j = threadIdx.x; j < N / 4; j += 256)
        ((float4*)vl)[j] = ((const float4*)v)[j];
    __syncthreads();
    const int w    = threadIdx.x >> 6;
    const int lane = threadIdx.x & 63;
    const int i    = blockIdx.x * 4 + w;
    const float4* krow = (const float4*)(K + (size_t)i * N);
    const float4* v4   = (const float4*)vl;
    float acc = 0.f;
    for (int c = lane; c < N / 4; c += 64) {
        float4 k  = krow[c];
        float4 vv = v4[c];
        acc += k.x * vv.x + k.y * vv.y + k.z * vv.z + k.w * vv.w;
    }
    for (int off = 32; off > 0; off >>= 1)
        acc += __shfl_down(acc, off, 64);
    if (lane == 0) {
        float un = av[i] / (acc + EPSV);
        float d  = un - u[i];
        du2[i] = d * d;
        u[i]   = un;
    }
}

__global__ __launch_bounds__(256)
void k_err(const float* __restrict__ du2, int* __restrict__ flag)
{
    if (*flag) return;
    __shared__ float r[4];
    float s = 0.f;
    for (int i = threadIdx.x; i < N; i += 256) s += du2[i];
    for (int off = 32; off > 0; off >>= 1)
        s += __shfl_down(s, off, 64);
    if ((threadIdx.x & 63) == 0) r[threadIdx.x >> 6] = s;
    __syncthreads();
    if (threadIdx.x == 0) {
        float e = sqrtf(r[0] + r[1] + r[2] + r[3]);
        if (e < THRESH) *flag = 1;
    }
}

__global__ __launch_bounds__(256)
void k_final(float* __restrict__ K, const float* __restrict__ u,
             const float* __restrict__ v)
{
    __shared__ __align__(16) float vl[N];
    for (int j = threadIdx.x; j < N / 4; j += 256)
        ((float4*)vl)[j] = ((const float4*)v)[j];
    __syncthreads();
    const int w    = threadIdx.x >> 6;
    const int lane = threadIdx.x & 63;
    const int i    = blockIdx.x * 4 + w;
    const float ui = u[i];
    float4* krow = (float4*)(K + (size_t)i * N);
    const float4* v4 = (const float4*)vl;
    for (int c = lane; c < N / 4; c += 64) {
        float4 k  = krow[c];
        float4 vv = v4[c];
        k.x *= ui * vv.x; k.y *= ui * vv.y; k.z *= ui * vv.z; k.w *= ui * vv.w;
        krow[c] = k;
    }
}

// ===========================================================================
extern "C" void kernel_launch(void* const* d_in, const int* in_sizes, int n_in,
                              void* d_out, int out_size, void* d_ws, size_t ws_size,
                              hipStream_t stream)
{
    const float* cost = (const float*)d_in[0];
    const float* av   = (const float*)d_in[1];
    const float* bv   = (const float*)d_in[2];
    float* out = (float*)d_out;

    // ws layout: u32[N] | v32[N] | bsum[256] | bar(64B slot) | u16[N] | v16[N] | K8 | KT8
    float*        u32  = (float*)d_ws;
    float*        v32  = u32 + N;
    float*        bsum = v32 + N;
    unsigned int* bar  = (unsigned int*)(bsum + 256);
    __half*       u16  = (__half*)(bar + 16);
    __half*       v16  = u16 + N;
    unsigned char* base = (unsigned char*)(v16 + N);
    const size_t  head  = (size_t)((unsigned char*)base - (unsigned char*)d_ws);
    const size_t  szK8  = (size_t)N * N;
    const size_t  need8 = head + 2 * szK8;    // ~128 MB

    if (ws_size >= need8) {
        unsigned char* K8  = base;
        unsigned char* KT8 = base + szK8;
        k_init8<<<dim3(64, 64), NTHR, 0, stream>>>(cost, K8, KT8, u32, u16, bar);
        sinkhorn_loop8<<<LBLK, LTHR, 0, stream>>>(av, bv, u32, v32, u16, v16,
                                                  bsum, bar, K8, KT8);
        k_output<<<2048, NTHR, 0, stream>>>(cost, u32, v32, out);
        return;
    }

    // ---- tier 3: proven multi-kernel fp32 path ----
    int*   flag    = (int*)d_ws;
    float* uf      = (float*)d_ws + 16;
    float* vf      = uf + N;
    float* du2f    = vf + N;
    float* partial = du2f + N;

    k_init<<<2048, 256, 0, stream>>>(cost, out, uf, flag);
    for (int it = 0; it < MAX_IT; ++it) {
        k_colmv<<<1024, 256, 0, stream>>>(out, uf, partial, flag);
        k_v    <<<  32, 256, 0, stream>>>(partial, bv, vf, flag);
        k_rowmv<<<2048, 256, 0, stream>>>(out, av, vf, uf, du2f, flag);
        k_err  <<<   1, 256, 0, stream>>>(du2f, flag);
    }
    k_final<<<2048, 256, 0, stream>>>(out, uf, vf);
}

// Round 13
// 557.148 us; speedup vs baseline: 1.8529x; 1.1079x over previous
//
#include <hip/hip_runtime.h>
#include <hip/hip_fp16.h>

typedef float fx2 __attribute__((ext_vector_type(2)));
typedef float fx4 __attribute__((ext_vector_type(4)));

constexpr int   N       = 8192;
constexpr float INV_REG = 10.0f;    // 1/REG
constexpr float THRESH  = 1e-3f;
constexpr float EPSV    = 1e-8f;
constexpr int   MAX_IT  = 100;
constexpr int   NTHR    = 256;      // block size for init/output kernels
constexpr int   LTHR    = 1024;     // loop block size (16 waves)
constexpr int   LBLK    = 256;      // loop grid; capacity 2/CU -> always resident

// ---------------- fp8 e4m3 (OCP) helpers ----------------------------------
#if defined(__HIP_DEVICE_COMPILE__) && __has_builtin(__builtin_amdgcn_cvt_pk_f32_fp8) && __has_builtin(__builtin_amdgcn_cvt_pk_fp8_f32)
#define FP8_HW 1
#else
#define FP8_HW 0
#endif

template <bool HI>
__device__ __forceinline__ fx2 fp8x2_dec(unsigned int w)
{
#if FP8_HW
    return __builtin_amdgcn_cvt_pk_f32_fp8((int)w, HI);
#else
    unsigned int s = HI ? (w >> 16) : (w & 0xFFFFu);
    unsigned int b0 = s & 0xFFu, b1 = (s >> 8) & 0xFFu;
    unsigned int e0 = (b0 >> 3) & 0xFu, m0 = b0 & 7u;
    unsigned int e1 = (b1 >> 3) & 0xFu, m1 = b1 & 7u;
    fx2 r;
    r.x = e0 ? __builtin_bit_cast(float, ((e0 + 120u) << 23) | (m0 << 20))
             : (float)m0 * 0.001953125f;
    r.y = e1 ? __builtin_bit_cast(float, ((e1 + 120u) << 23) | (m1 << 20))
             : (float)m1 * 0.001953125f;
    return r;
#endif
}

__device__ __forceinline__ unsigned int fp8_enc1(float x)
{
    if (x < 0.015625f) return (unsigned int)(int)rintf(x * 512.0f);
    unsigned int bits = __builtin_bit_cast(unsigned int, x);
    unsigned int e = bits >> 23;
    unsigned int m = bits & 0x7FFFFFu;
    m += 0x7FFFFu + ((m >> 20) & 1u);
    if (m >> 23) { m = 0; e += 1; }
    return ((e - 120u) << 3) | (m >> 20);
}

__device__ __forceinline__ unsigned int fp8x4_enc(float a, float b, float c, float d)
{
#if FP8_HW
    int w = __builtin_amdgcn_cvt_pk_fp8_f32(a, b, 0, false);
    w     = __builtin_amdgcn_cvt_pk_fp8_f32(c, d, w, true);
    return (unsigned int)w;
#else
    return fp8_enc1(a) | (fp8_enc1(b) << 8) | (fp8_enc1(c) << 16) | (fp8_enc1(d) << 24);
#endif
}

__device__ __forceinline__ float2 h2f2(unsigned int h)
{
    return __half22float2(*reinterpret_cast<const __half2*>(&h));
}

__device__ __forceinline__ float wave_sum(float x)
{
    #pragma unroll
    for (int off = 32; off > 0; off >>= 1) x += __shfl_down(x, off, 64);
    return x;  // lane 0 holds the sum
}

// Manual grid barrier, cg-equivalent cost profile:
//  - arrive: ONE agent-scope RELEASE fetch_add (one L2 writeback per block)
//  - poll:   RELAXED agent loads (scope bits make remote increments visible,
//            ordering adds NO cache invalidate -> no per-poll L2 inv)
//  - depart: ONE agent-scope ACQUIRE load (one L1+L2 invalidate per block)
// R12's bug: acquire-per-poll invalidated the XCD L2 every ~50ns grid-wide.
__device__ __forceinline__ void grid_barrier(unsigned int* bar, unsigned int target)
{
    __syncthreads();                 // drain block's mem ops (vmcnt/lgkmcnt 0)
    if (threadIdx.x == 0) {
        __hip_atomic_fetch_add(bar, 1u, __ATOMIC_RELEASE, __HIP_MEMORY_SCOPE_AGENT);
        while (__hip_atomic_load(bar, __ATOMIC_RELAXED, __HIP_MEMORY_SCOPE_AGENT) < target)
            __builtin_amdgcn_s_sleep(8);
        (void)__hip_atomic_load(bar, __ATOMIC_ACQUIRE, __HIP_MEMORY_SCOPE_AGENT);
    }
    __syncthreads();
}

// full-row fp8 dot: pre-issue ALL 8 row loads (128 B/lane in flight), then
// consume against LDS-staged fp16 vector.
__device__ __forceinline__ float dot_fp8_row(const unsigned char* __restrict__ row,
                                             const __half* __restrict__ sv, int lane)
{
    const uint4* r4 = (const uint4*)row;   // 512 x 16 fp8
    const uint4* s4 = (const uint4*)sv;    // 1024 x 8 halves
    uint4 kk[8];
    #pragma unroll
    for (int t = 0; t < 8; ++t) kk[t] = r4[lane + 64 * t];

    float a0 = 0.f, a1 = 0.f, a2 = 0.f, a3 = 0.f;
    #pragma unroll
    for (int t = 0; t < 8; ++t) {
        const int c = lane + 64 * t;
        uint4 h0 = s4[2 * c];
        uint4 h1 = s4[2 * c + 1];
        fx2 f; float2 g;
        f = fp8x2_dec<false>(kk[t].x); g = h2f2(h0.x); a0 += f.x * g.x; a1 += f.y * g.y;
        f = fp8x2_dec<true >(kk[t].x); g = h2f2(h0.y); a2 += f.x * g.x; a3 += f.y * g.y;
        f = fp8x2_dec<false>(kk[t].y); g = h2f2(h0.z); a0 += f.x * g.x; a1 += f.y * g.y;
        f = fp8x2_dec<true >(kk[t].y); g = h2f2(h0.w); a2 += f.x * g.x; a3 += f.y * g.y;
        f = fp8x2_dec<false>(kk[t].z); g = h2f2(h1.x); a0 += f.x * g.x; a1 += f.y * g.y;
        f = fp8x2_dec<true >(kk[t].z); g = h2f2(h1.y); a2 += f.x * g.x; a3 += f.y * g.y;
        f = fp8x2_dec<false>(kk[t].w); g = h2f2(h1.z); a0 += f.x * g.x; a1 += f.y * g.y;
        f = fp8x2_dec<true >(kk[t].w); g = h2f2(h1.w); a2 += f.x * g.x; a3 += f.y * g.y;
    }
    return (a0 + a1) + (a2 + a3);
}

// ===========================================================================
// init: K8 = fp8(exp(-cost/REG)) row-major AND KT8 = fp8 transposed, via
// 128x128 byte LDS tile. u32/u16 = 1/N; barrier counter = 0 (every replay).
// grid = (64,64) x 256.
// ===========================================================================
__global__ __launch_bounds__(NTHR)
void k_init8(const float* __restrict__ cost, unsigned char* __restrict__ K8,
             unsigned char* __restrict__ KT8, float* __restrict__ u32,
             __half* __restrict__ u16, unsigned int* __restrict__ bar)
{
    __shared__ unsigned char tile[128][132];   // +4 pad
    const int r0 = blockIdx.y << 7;
    const int c0 = blockIdx.x << 7;
    const int tx = threadIdx.x & 31;    // 32 x 4 cols = 128
    const int ty = threadIdx.x >> 5;    // 8 rows / pass

    for (int p = 0; p < 16; ++p) {
        const int r = p * 8 + ty;
        fx4 c = __builtin_nontemporal_load(
            (const fx4*)(cost + (size_t)(r0 + r) * N + c0) + tx);
        unsigned int enc = fp8x4_enc(__expf(-INV_REG * c.x), __expf(-INV_REG * c.y),
                                     __expf(-INV_REG * c.z), __expf(-INV_REG * c.w));
        ((unsigned int*)(K8 + (size_t)(r0 + r) * N + c0))[tx] = enc;
        *(unsigned int*)&tile[r][tx * 4] = enc;
    }
    __syncthreads();

    for (int p = 0; p < 16; ++p) {
        const int c = p * 8 + ty;       // tile col == KT8 row
        unsigned int w = (unsigned int)tile[tx * 4 + 0][c]
                       | ((unsigned int)tile[tx * 4 + 1][c] << 8)
                       | ((unsigned int)tile[tx * 4 + 2][c] << 16)
                       | ((unsigned int)tile[tx * 4 + 3][c] << 24);
        ((unsigned int*)(KT8 + (size_t)(c0 + c) * N + r0))[tx] = w;
    }

    if (blockIdx.y == 0 && blockIdx.x < 32) {
        const int g = blockIdx.x * NTHR + threadIdx.x;
        u32[g] = 1.0f / (float)N;
        u16[g] = __float2half(1.0f / (float)N);   // 2^-13, exact in fp16
    }
    if (blockIdx.x == 0 && blockIdx.y == 0 && threadIdx.x == 0)
        __hip_atomic_store(bar, 0u, __ATOMIC_RELEASE, __HIP_MEMORY_SCOPE_AGENT);
}

// ===========================================================================
// loop: PLAIN launch, 256 blocks x 1024 threads, manual grid barrier.
// 2 barriers/iter. Per phase each wave handles 2 rows.
//   A: v[j] = b[j]/(KT8[j,:].u16 + eps)
//   B: u[i] = a[i]/(K8 [i,:].v16 + eps); block-partial d^2 -> bsum[bid]
//   C: all blocks reduce bsum[0..255] in identical order -> same exit bit
// __launch_bounds__(1024, 8): forces VGPR<=64 -> 2 blocks/CU capacity ->
// all 256 blocks resident under any dispatch skew (>=128 CUs suffice).
// ===========================================================================
__global__ __launch_bounds__(LTHR, 8)
void sinkhorn_loop8(const float* __restrict__ av, const float* __restrict__ bv,
                    float* __restrict__ u32, float* __restrict__ v32,
                    __half* __restrict__ u16, __half* __restrict__ v16,
                    float* __restrict__ bsum, unsigned int* __restrict__ bar,
                    const unsigned char* __restrict__ K8,
                    const unsigned char* __restrict__ KT8)
{
    const int tid  = threadIdx.x;
    const int bid  = blockIdx.x;
    const int nblk = gridDim.x;               // 256
    const int rpb  = N / nblk;                // 32 rows/block
    const int nw   = LTHR / 64;               // 16 waves
    const int pw   = rpb / nw;                // 2 rows/wave
    const int w    = tid >> 6;
    const int lane = tid & 63;

    __shared__ __align__(16) __half stage[N];   // 16 KB
    __shared__ float red[16];
    __shared__ float err_sh;

    unsigned int gen = 0;
    int iter = 0;
    while (true) {
        // ---- A: v-update over KT8 rows ----
        ((uint4*)stage)[tid] = ((const uint4*)u16)[tid];   // N/8 == LTHR
        __syncthreads();
        for (int rr = 0; rr < pw; ++rr) {
            const int j = bid * rpb + w * pw + rr;
            float acc = dot_fp8_row(KT8 + (size_t)j * N, stage, lane);
            acc = wave_sum(acc);
            if (lane == 0) {
                float vn = bv[j] / (acc + EPSV);
                v32[j] = vn;
                v16[j] = __float2half(vn);
            }
        }
        ++gen;
        grid_barrier(bar, (unsigned int)nblk * gen);

        // ---- B: u-update over K8 rows + block-partial d^2 ----
        ((uint4*)stage)[tid] = ((const uint4*)v16)[tid];
        __syncthreads();
        float mydu = 0.f;
        for (int rr = 0; rr < pw; ++rr) {
            const int i = bid * rpb + w * pw + rr;
            float acc = dot_fp8_row(K8 + (size_t)i * N, stage, lane);
            acc = wave_sum(acc);
            if (lane == 0) {
                float un = av[i] / (acc + EPSV);
                float d  = un - u32[i];
                mydu += d * d;
                u32[i] = un;
                u16[i] = __float2half(un);
            }
        }
        if (lane == 0) red[w] = mydu;
        __syncthreads();
        if (tid == 0) {
            float s = 0.f;
            #pragma unroll
            for (int t = 0; t < 16; ++t) s += red[t];
            bsum[bid] = s;
        }
        ++gen;
        grid_barrier(bar, (unsigned int)nblk * gen);

        // ---- C: every block reduces bsum[0..nblk) identically ----
        {
            float s = (tid < nblk) ? bsum[tid] : 0.f;
            s = wave_sum(s);
            if (lane == 0) red[w] = s;
            __syncthreads();
            if (tid == 0) {
                float t0 = 0.f;
                #pragma unroll
                for (int t = 0; t < 16; ++t) t0 += red[t];
                err_sh = sqrtf(t0);
            }
            __syncthreads();
            float err = err_sh;
            ++iter;
            if (iter >= MAX_IT || err < THRESH) break;
        }
        // C->A safe: next B's bsum writes happen only after barrier #1, which
        // requires every block to have finished its C-phase bsum reads.
    }
}

// ===========================================================================
// output: out[i][j] = u_i * exp(-cost_ij/REG) * v_j (exact fp32 K recompute)
// ===========================================================================
__global__ __launch_bounds__(NTHR)
void k_output(const float* __restrict__ cost, const float* __restrict__ u,
              const float* __restrict__ v, float* __restrict__ out)
{
    __shared__ __align__(16) float vl[N];
    for (int j = threadIdx.x; j < N / 4; j += NTHR)
        ((float4*)vl)[j] = ((const float4*)v)[j];
    __syncthreads();

    const int w    = threadIdx.x >> 6;
    const int lane = threadIdx.x & 63;
    const int i    = blockIdx.x * 4 + w;
    const float ui = u[i];
    const fx4* crow = (const fx4*)(cost + (size_t)i * N);
    fx4*       orow = (fx4*)(out + (size_t)i * N);
    #pragma unroll 4
    for (int c = lane; c < N / 4; c += 64) {
        fx4 cc = __builtin_nontemporal_load(&crow[c]);
        float4 vv = ((const float4*)vl)[c];
        fx4 o;
        o.x = ui * __expf(-INV_REG * cc.x) * vv.x;
        o.y = ui * __expf(-INV_REG * cc.y) * vv.y;
        o.z = ui * __expf(-INV_REG * cc.z) * vv.z;
        o.w = ui * __expf(-INV_REG * cc.w) * vv.w;
        __builtin_nontemporal_store(o, &orow[c]);
    }
}

// ===========================================================================
// Tier-3 fallback (round-2 proven multi-kernel, fp32 K in d_out) — only if
// ws_size can't hold the fp8 shadows (never observed; ws >= 192 MB).
// ===========================================================================
constexpr int NSLAB_F = 64;

__global__ __launch_bounds__(256)
void k_init(const float* __restrict__ cost, float* __restrict__ K,
            float* __restrict__ u, int* __restrict__ flag)
{
    const int gtid = blockIdx.x * 256 + threadIdx.x;
    const int gsz  = gridDim.x * 256;
    const float4* c4 = (const float4*)cost;
    float4*       k4 = (float4*)K;
    const int tot4 = N * N / 4;
    for (int i = gtid; i < tot4; i += gsz) {
        float4 c = c4[i];
        float4 k;
        k.x = __expf(-INV_REG * c.x);
        k.y = __expf(-INV_REG * c.y);
        k.z = __expf(-INV_REG * c.z);
        k.w = __expf(-INV_REG * c.w);
        k4[i] = k;
    }
    if (gtid < N) u[gtid] = 1.0f / (float)N;
    if (gtid == 0) *flag = 0;
}

__global__ __launch_bounds__(256)
void k_colmv(const float* __restrict__ K, const float* __restrict__ u,
             float* __restrict__ partial, const int* __restrict__ flag)
{
    if (*flag) return;
    __shared__ float  uh[128];
    __shared__ __align__(16) float4 accs[128];
    const int rs = blockIdx.x >> 4;
    const int cs = blockIdx.x & 15;
    const int r0 = rs * 128;
    const int c0 = cs * 512;
    const int l  = threadIdx.x & 127;
    const int h  = threadIdx.x >> 7;
    if (threadIdx.x < 128) uh[threadIdx.x] = u[r0 + threadIdx.x];
    __syncthreads();
    float4 acc = make_float4(0.f, 0.f, 0.f, 0.f);
    for (int r = h; r < 128; r += 2) {
        float4 k = ((const float4*)(K + (size_t)(r0 + r) * N))[(c0 >> 2) + l];
        float uu = uh[r];
        acc.x += k.x * uu; acc.y += k.y * uu; acc.z += k.z * uu; acc.w += k.w * uu;
    }
    if (h == 1) accs[l] = acc;
    __syncthreads();
    if (h == 0) {
        float4 o = accs[l];
        acc.x += o.x; acc.y += o.y; acc.z += o.z; acc.w += o.w;
        ((float4*)(partial + (size_t)rs * N + c0))[l] = acc;
    }
}

__global__ __launch_bounds__(256)
void k_v(const float* __restrict__ partial, const float* __restrict__ bv,
         float* __restrict__ v, const int* __restrict__ flag)
{
    if (*flag) return;
    const int j = blockIdx.x * 256 + threadIdx.x;
    float s = 0.f;
    for (int sl = 0; sl < NSLAB_F; ++sl) s += partial[(size_t)sl * N + j];
    v[j] = bv[j] / (s + EPSV);
}

__global__ __launch_bounds__(256)
void k_rowmv(const float* __restrict__ K, const float* __restrict__ av,
             const float* __restrict__ v, float* __restrict__ u,
             float* __restrict__ du2, const int* __restrict__ flag)
{
    if (*flag) return;
    __shared__ __align__(16) float vl[N];
    for (int j = threadIdx.x; j < N / 4; j += 256)
        ((float4*)vl)[j] = ((const float4*)v)[j];
    __syncthreads();
    const int w    = threadIdx.x >> 6;
    const int lane = threadIdx.x & 63;
    const int i    = blockIdx.x * 4 + w;
    const float4* krow = (const float4*)(K + (size_t)i * N);
    const float4* v4   = (const float4*)vl;
    float acc = 0.f;
    for (int c = lane; c < N / 4; c += 64) {
        float4 k  = krow[c];
        float4 vv = v4[c];
        acc += k.x * vv.x + k.y * vv.y + k.z * vv.z + k.w * vv.w;
    }
    for (int off = 32; off > 0; off >>= 1)
        acc += __shfl_down(acc, off, 64);
    if (lane == 0) {
        float un = av[i] / (acc + EPSV);
        float d  = un - u[i];
        du2[i] = d * d;
        u[i]   = un;
    }
}

__global__ __launch_bounds__(256)
void k_err(const float* __restrict__ du2, int* __restrict__ flag)
{
    if (*flag) return;
    __shared__ float r[4];
    float s = 0.f;
    for (int i = threadIdx.x; i < N; i += 256) s += du2[i];
    for (int off = 32; off > 0; off >>= 1)
        s += __shfl_down(s, off, 64);
    if ((threadIdx.x & 63) == 0) r[threadIdx.x >> 6] = s;
    __syncthreads();
    if (threadIdx.x == 0) {
        float e = sqrtf(r[0] + r[1] + r[2] + r[3]);
        if (e < THRESH) *flag = 1;
    }
}

__global__ __launch_bounds__(256)
void k_final(float* __restrict__ K, const float* __restrict__ u,
             const float* __restrict__ v)
{
    __shared__ __align__(16) float vl[N];
    for (int j = threadIdx.x; j < N / 4; j += 256)
        ((float4*)vl)[j] = ((const float4*)v)[j];
    __syncthreads();
    const int w    = threadIdx.x >> 6;
    const int lane = threadIdx.x & 63;
    const int i    = blockIdx.x * 4 + w;
    const float ui = u[i];
    float4* krow = (float4*)(K + (size_t)i * N);
    const float4* v4 = (const float4*)vl;
    for (int c = lane; c < N / 4; c += 64) {
        float4 k  = krow[c];
        float4 vv = v4[c];
        k.x *= ui * vv.x; k.y *= ui * vv.y; k.z *= ui * vv.z; k.w *= ui * vv.w;
        krow[c] = k;
    }
}

// ===========================================================================
extern "C" void kernel_launch(void* const* d_in, const int* in_sizes, int n_in,
                              void* d_out, int out_size, void* d_ws, size_t ws_size,
                              hipStream_t stream)
{
    const float* cost = (const float*)d_in[0];
    const float* av   = (const float*)d_in[1];
    const float* bv   = (const float*)d_in[2];
    float* out = (float*)d_out;

    // ws layout: u32[N] | v32[N] | bsum[256] | bar(64B slot) | u16[N] | v16[N] | K8 | KT8
    float*        u32  = (float*)d_ws;
    float*        v32  = u32 + N;
    float*        bsum = v32 + N;
    unsigned int* bar  = (unsigned int*)(bsum + 256);
    __half*       u16  = (__half*)(bar + 16);
    __half*       v16  = u16 + N;
    unsigned char* base = (unsigned char*)(v16 + N);
    const size_t  head  = (size_t)((unsigned char*)base - (unsigned char*)d_ws);
    const size_t  szK8  = (size_t)N * N;
    const size_t  need8 = head + 2 * szK8;    // ~128 MB

    if (ws_size >= need8) {
        unsigned char* K8  = base;
        unsigned char* KT8 = base + szK8;
        k_init8<<<dim3(64, 64), NTHR, 0, stream>>>(cost, K8, KT8, u32, u16, bar);
        sinkhorn_loop8<<<LBLK, LTHR, 0, stream>>>(av, bv, u32, v32, u16, v16,
                                                  bsum, bar, K8, KT8);
        k_output<<<2048, NTHR, 0, stream>>>(cost, u32, v32, out);
        return;
    }

    // ---- tier 3: proven multi-kernel fp32 path ----
    int*   flag    = (int*)d_ws;
    float* uf      = (float*)d_ws + 16;
    float* vf      = uf + N;
    float* du2f    = vf + N;
    float* partial = du2f + N;

    k_init<<<2048, 256, 0, stream>>>(cost, out, uf, flag);
    for (int it = 0; it < MAX_IT; ++it) {
        k_colmv<<<1024, 256, 0, stream>>>(out, uf, partial, flag);
        k_v    <<<  32, 256, 0, stream>>>(partial, bv, vf, flag);
        k_rowmv<<<2048, 256, 0, stream>>>(out, av, vf, uf, du2f, flag);
        k_err  <<<   1, 256, 0, stream>>>(du2f, flag);
    }
    k_final<<<2048, 256, 0, stream>>>(out, uf, vf);
}

// Round 14
// 408.154 us; speedup vs baseline: 2.5293x; 1.3650x over previous
//
#include <hip/hip_runtime.h>
#include <hip/hip_fp16.h>

typedef float fx2 __attribute__((ext_vector_type(2)));
typedef float fx4 __attribute__((ext_vector_type(4)));

constexpr int   N       = 8192;
constexpr float INV_REG = 10.0f;    // 1/REG
constexpr float THRESH  = 1e-3f;
constexpr float EPSV    = 1e-8f;
constexpr int   MAX_IT  = 100;
constexpr int   NTHR    = 256;      // block size for init/output kernels
constexpr int   LTHR    = 1024;     // loop block size (16 waves)
constexpr int   LBLK    = 256;      // loop grid: 1 block/CU, all co-resident

// ---------------- fp8 e4m3 (OCP) helpers ----------------------------------
#if defined(__HIP_DEVICE_COMPILE__) && __has_builtin(__builtin_amdgcn_cvt_pk_f32_fp8) && __has_builtin(__builtin_amdgcn_cvt_pk_fp8_f32)
#define FP8_HW 1
#else
#define FP8_HW 0
#endif

template <bool HI>
__device__ __forceinline__ fx2 fp8x2_dec(unsigned int w)
{
#if FP8_HW
    return __builtin_amdgcn_cvt_pk_f32_fp8((int)w, HI);
#else
    unsigned int s = HI ? (w >> 16) : (w & 0xFFFFu);
    unsigned int b0 = s & 0xFFu, b1 = (s >> 8) & 0xFFu;
    unsigned int e0 = (b0 >> 3) & 0xFu, m0 = b0 & 7u;
    unsigned int e1 = (b1 >> 3) & 0xFu, m1 = b1 & 7u;
    fx2 r;
    r.x = e0 ? __builtin_bit_cast(float, ((e0 + 120u) << 23) | (m0 << 20))
             : (float)m0 * 0.001953125f;
    r.y = e1 ? __builtin_bit_cast(float, ((e1 + 120u) << 23) | (m1 << 20))
             : (float)m1 * 0.001953125f;
    return r;
#endif
}

__device__ __forceinline__ unsigned int fp8_enc1(float x)
{
    if (x < 0.015625f) return (unsigned int)(int)rintf(x * 512.0f);
    unsigned int bits = __builtin_bit_cast(unsigned int, x);
    unsigned int e = bits >> 23;
    unsigned int m = bits & 0x7FFFFFu;
    m += 0x7FFFFu + ((m >> 20) & 1u);
    if (m >> 23) { m = 0; e += 1; }
    return ((e - 120u) << 3) | (m >> 20);
}

__device__ __forceinline__ unsigned int fp8x4_enc(float a, float b, float c, float d)
{
#if FP8_HW
    int w = __builtin_amdgcn_cvt_pk_fp8_f32(a, b, 0, false);
    w     = __builtin_amdgcn_cvt_pk_fp8_f32(c, d, w, true);
    return (unsigned int)w;
#else
    return fp8_enc1(a) | (fp8_enc1(b) << 8) | (fp8_enc1(c) << 16) | (fp8_enc1(d) << 24);
#endif
}

__device__ __forceinline__ float2 h2f2(unsigned int h)
{
    return __half22float2(*reinterpret_cast<const __half2*>(&h));
}

__device__ __forceinline__ float wave_sum(float x)
{
    #pragma unroll
    for (int off = 32; off > 0; off >>= 1) x += __shfl_down(x, off, 64);
    return x;  // lane 0 holds the sum
}

// Manual grid barrier (cg-equivalent cost):
//  arrive = ONE agent-scope RELEASE fetch_add; poll = RELAXED agent loads
//  (no cache-inv per poll); depart = ONE agent-scope ACQUIRE load.
__device__ __forceinline__ void grid_barrier(unsigned int* bar, unsigned int target)
{
    __syncthreads();
    if (threadIdx.x == 0) {
        __hip_atomic_fetch_add(bar, 1u, __ATOMIC_RELEASE, __HIP_MEMORY_SCOPE_AGENT);
        while (__hip_atomic_load(bar, __ATOMIC_RELAXED, __HIP_MEMORY_SCOPE_AGENT) < target)
            __builtin_amdgcn_s_sleep(8);
        (void)__hip_atomic_load(bar, __ATOMIC_ACQUIRE, __HIP_MEMORY_SCOPE_AGENT);
    }
    __syncthreads();
}

// full-row fp8 dot: pre-issue ALL 8 row loads (128 B/lane in flight; needs
// 32 VGPRs live for kk[] -> loop kernel must allow >=64 VGPRs), then consume
// against the LDS-staged fp16 vector.
__device__ __forceinline__ float dot_fp8_row(const unsigned char* __restrict__ row,
                                             const __half* __restrict__ sv, int lane)
{
    const uint4* r4 = (const uint4*)row;   // 512 x 16 fp8
    const uint4* s4 = (const uint4*)sv;    // 1024 x 8 halves
    uint4 kk[8];
    #pragma unroll
    for (int t = 0; t < 8; ++t) kk[t] = r4[lane + 64 * t];

    float a0 = 0.f, a1 = 0.f, a2 = 0.f, a3 = 0.f;
    #pragma unroll
    for (int t = 0; t < 8; ++t) {
        const int c = lane + 64 * t;
        uint4 h0 = s4[2 * c];
        uint4 h1 = s4[2 * c + 1];
        fx2 f; float2 g;
        f = fp8x2_dec<false>(kk[t].x); g = h2f2(h0.x); a0 += f.x * g.x; a1 += f.y * g.y;
        f = fp8x2_dec<true >(kk[t].x); g = h2f2(h0.y); a2 += f.x * g.x; a3 += f.y * g.y;
        f = fp8x2_dec<false>(kk[t].y); g = h2f2(h0.z); a0 += f.x * g.x; a1 += f.y * g.y;
        f = fp8x2_dec<true >(kk[t].y); g = h2f2(h0.w); a2 += f.x * g.x; a3 += f.y * g.y;
        f = fp8x2_dec<false>(kk[t].z); g = h2f2(h1.x); a0 += f.x * g.x; a1 += f.y * g.y;
        f = fp8x2_dec<true >(kk[t].z); g = h2f2(h1.y); a2 += f.x * g.x; a3 += f.y * g.y;
        f = fp8x2_dec<false>(kk[t].w); g = h2f2(h1.z); a0 += f.x * g.x; a1 += f.y * g.y;
        f = fp8x2_dec<true >(kk[t].w); g = h2f2(h1.w); a2 += f.x * g.x; a3 += f.y * g.y;
    }
    return (a0 + a1) + (a2 + a3);
}

// ===========================================================================
// init: K8 = fp8(exp(-cost/REG)) row-major AND KT8 = fp8 transposed, via
// 128x128 byte LDS tile. u32/u16 = 1/N; barrier counter = 0 (every replay).
// grid = (64,64) x 256.
// ===========================================================================
__global__ __launch_bounds__(NTHR)
void k_init8(const float* __restrict__ cost, unsigned char* __restrict__ K8,
             unsigned char* __restrict__ KT8, float* __restrict__ u32,
             __half* __restrict__ u16, unsigned int* __restrict__ bar)
{
    __shared__ unsigned char tile[128][132];   // +4 pad
    const int r0 = blockIdx.y << 7;
    const int c0 = blockIdx.x << 7;
    const int tx = threadIdx.x & 31;    // 32 x 4 cols = 128
    const int ty = threadIdx.x >> 5;    // 8 rows / pass

    for (int p = 0; p < 16; ++p) {
        const int r = p * 8 + ty;
        fx4 c = __builtin_nontemporal_load(
            (const fx4*)(cost + (size_t)(r0 + r) * N + c0) + tx);
        unsigned int enc = fp8x4_enc(__expf(-INV_REG * c.x), __expf(-INV_REG * c.y),
                                     __expf(-INV_REG * c.z), __expf(-INV_REG * c.w));
        ((unsigned int*)(K8 + (size_t)(r0 + r) * N + c0))[tx] = enc;
        *(unsigned int*)&tile[r][tx * 4] = enc;
    }
    __syncthreads();

    for (int p = 0; p < 16; ++p) {
        const int c = p * 8 + ty;       // tile col == KT8 row
        unsigned int w = (unsigned int)tile[tx * 4 + 0][c]
                       | ((unsigned int)tile[tx * 4 + 1][c] << 8)
                       | ((unsigned int)tile[tx * 4 + 2][c] << 16)
                       | ((unsigned int)tile[tx * 4 + 3][c] << 24);
        ((unsigned int*)(KT8 + (size_t)(c0 + c) * N + r0))[tx] = w;
    }

    if (blockIdx.y == 0 && blockIdx.x < 32) {
        const int g = blockIdx.x * NTHR + threadIdx.x;
        u32[g] = 1.0f / (float)N;
        u16[g] = __float2half(1.0f / (float)N);   // 2^-13, exact in fp16
    }
    if (blockIdx.x == 0 && blockIdx.y == 0 && threadIdx.x == 0)
        __hip_atomic_store(bar, 0u, __ATOMIC_RELEASE, __HIP_MEMORY_SCOPE_AGENT);
}

// ===========================================================================
// loop: PLAIN launch, 256 blocks x 1024 threads, manual grid barrier.
// 2 barriers/iter; 2 rows/wave/phase.
// __launch_bounds__(1024, 4): VGPR cap 128 (compiler lands ~64, kk[8] stays
// fully live -> 8 loads in flight). k = 4*4/(1024/64) = 1 block/CU -> all
// 256 blocks co-resident on 256 CUs (barrier-safe).
// ===========================================================================
__global__ __launch_bounds__(LTHR, 4)
void sinkhorn_loop8(const float* __restrict__ av, const float* __restrict__ bv,
                    float* __restrict__ u32, float* __restrict__ v32,
                    __half* __restrict__ u16, __half* __restrict__ v16,
                    float* __restrict__ bsum, unsigned int* __restrict__ bar,
                    const unsigned char* __restrict__ K8,
                    const unsigned char* __restrict__ KT8)
{
    const int tid  = threadIdx.x;
    const int bid  = blockIdx.x;
    const int nblk = gridDim.x;               // 256
    const int rpb  = N / nblk;                // 32 rows/block
    const int nw   = LTHR / 64;               // 16 waves
    const int pw   = rpb / nw;                // 2 rows/wave
    const int w    = tid >> 6;
    const int lane = tid & 63;

    __shared__ __align__(16) __half stage[N];   // 16 KB
    __shared__ float red[16];
    __shared__ float err_sh;

    unsigned int gen = 0;
    int iter = 0;
    while (true) {
        // ---- A: v-update over KT8 rows ----
        ((uint4*)stage)[tid] = ((const uint4*)u16)[tid];   // N/8 == LTHR
        __syncthreads();
        for (int rr = 0; rr < pw; ++rr) {
            const int j = bid * rpb + w * pw + rr;
            float acc = dot_fp8_row(KT8 + (size_t)j * N, stage, lane);
            acc = wave_sum(acc);
            if (lane == 0) {
                float vn = bv[j] / (acc + EPSV);
                v32[j] = vn;
                v16[j] = __float2half(vn);
            }
        }
        ++gen;
        grid_barrier(bar, (unsigned int)nblk * gen);

        // ---- B: u-update over K8 rows + block-partial d^2 ----
        ((uint4*)stage)[tid] = ((const uint4*)v16)[tid];
        __syncthreads();
        float mydu = 0.f;
        for (int rr = 0; rr < pw; ++rr) {
            const int i = bid * rpb + w * pw + rr;
            float acc = dot_fp8_row(K8 + (size_t)i * N, stage, lane);
            acc = wave_sum(acc);
            if (lane == 0) {
                float un = av[i] / (acc + EPSV);
                float d  = un - u32[i];
                mydu += d * d;
                u32[i] = un;
                u16[i] = __float2half(un);
            }
        }
        if (lane == 0) red[w] = mydu;
        __syncthreads();
        if (tid == 0) {
            float s = 0.f;
            #pragma unroll
            for (int t = 0; t < 16; ++t) s += red[t];
            bsum[bid] = s;
        }
        ++gen;
        grid_barrier(bar, (unsigned int)nblk * gen);

        // ---- C: every block reduces bsum[0..nblk) identically ----
        {
            float s = (tid < nblk) ? bsum[tid] : 0.f;
            s = wave_sum(s);
            if (lane == 0) red[w] = s;
            __syncthreads();
            if (tid == 0) {
                float t0 = 0.f;
                #pragma unroll
                for (int t = 0; t < 16; ++t) t0 += red[t];
                err_sh = sqrtf(t0);
            }
            __syncthreads();
            float err = err_sh;
            ++iter;
            if (iter >= MAX_IT || err < THRESH) break;
        }
        // C->A safe: next B's bsum writes happen only after barrier #1.
    }
}

// ===========================================================================
// output: out[i][j] = u_i * exp(-cost_ij/REG) * v_j (exact fp32 K recompute)
// ===========================================================================
__global__ __launch_bounds__(NTHR)
void k_output(const float* __restrict__ cost, const float* __restrict__ u,
              const float* __restrict__ v, float* __restrict__ out)
{
    __shared__ __align__(16) float vl[N];
    for (int j = threadIdx.x; j < N / 4; j += NTHR)
        ((float4*)vl)[j] = ((const float4*)v)[j];
    __syncthreads();

    const int w    = threadIdx.x >> 6;
    const int lane = threadIdx.x & 63;
    const int i    = blockIdx.x * 4 + w;
    const float ui = u[i];
    const fx4* crow = (const fx4*)(cost + (size_t)i * N);
    fx4*       orow = (fx4*)(out + (size_t)i * N);
    #pragma unroll 4
    for (int c = lane; c < N / 4; c += 64) {
        fx4 cc = __builtin_nontemporal_load(&crow[c]);
        float4 vv = ((const float4*)vl)[c];
        fx4 o;
        o.x = ui * __expf(-INV_REG * cc.x) * vv.x;
        o.y = ui * __expf(-INV_REG * cc.y) * vv.y;
        o.z = ui * __expf(-INV_REG * cc.z) * vv.z;
        o.w = ui * __expf(-INV_REG * cc.w) * vv.w;
        __builtin_nontemporal_store(o, &orow[c]);
    }
}

// ===========================================================================
// Tier-3 fallback (round-2 proven multi-kernel, fp32 K in d_out) — only if
// ws_size can't hold the fp8 shadows (never observed; ws >= 192 MB).
// ===========================================================================
constexpr int NSLAB_F = 64;

__global__ __launch_bounds__(256)
void k_init(const float* __restrict__ cost, float* __restrict__ K,
            float* __restrict__ u, int* __restrict__ flag)
{
    const int gtid = blockIdx.x * 256 + threadIdx.x;
    const int gsz  = gridDim.x * 256;
    const float4* c4 = (const float4*)cost;
    float4*       k4 = (float4*)K;
    const int tot4 = N * N / 4;
    for (int i = gtid; i < tot4; i += gsz) {
        float4 c = c4[i];
        float4 k;
        k.x = __expf(-INV_REG * c.x);
        k.y = __expf(-INV_REG * c.y);
        k.z = __expf(-INV_REG * c.z);
        k.w = __expf(-INV_REG * c.w);
        k4[i] = k;
    }
    if (gtid < N) u[gtid] = 1.0f / (float)N;
    if (gtid == 0) *flag = 0;
}

__global__ __launch_bounds__(256)
void k_colmv(const float* __restrict__ K, const float* __restrict__ u,
             float* __restrict__ partial, const int* __restrict__ flag)
{
    if (*flag) return;
    __shared__ float  uh[128];
    __shared__ __align__(16) float4 accs[128];
    const int rs = blockIdx.x >> 4;
    const int cs = blockIdx.x & 15;
    const int r0 = rs * 128;
    const int c0 = cs * 512;
    const int l  = threadIdx.x & 127;
    const int h  = threadIdx.x >> 7;
    if (threadIdx.x < 128) uh[threadIdx.x] = u[r0 + threadIdx.x];
    __syncthreads();
    float4 acc = make_float4(0.f, 0.f, 0.f, 0.f);
    for (int r = h; r < 128; r += 2) {
        float4 k = ((const float4*)(K + (size_t)(r0 + r) * N))[(c0 >> 2) + l];
        float uu = uh[r];
        acc.x += k.x * uu; acc.y += k.y * uu; acc.z += k.z * uu; acc.w += k.w * uu;
    }
    if (h == 1) accs[l] = acc;
    __syncthreads();
    if (h == 0) {
        float4 o = accs[l];
        acc.x += o.x; acc.y += o.y; acc.z += o.z; acc.w += o.w;
        ((float4*)(partial + (size_t)rs * N + c0))[l] = acc;
    }
}

__global__ __launch_bounds__(256)
void k_v(const float* __restrict__ partial, const float* __restrict__ bv,
         float* __restrict__ v, const int* __restrict__ flag)
{
    if (*flag) return;
    const int j = blockIdx.x * 256 + threadIdx.x;
    float s = 0.f;
    for (int sl = 0; sl < NSLAB_F; ++sl) s += partial[(size_t)sl * N + j];
    v[j] = bv[j] / (s + EPSV);
}

__global__ __launch_bounds__(256)
void k_rowmv(const float* __restrict__ K, const float* __restrict__ av,
             const float* __restrict__ v, float* __restrict__ u,
             float* __restrict__ du2, const int* __restrict__ flag)
{
    if (*flag) return;
    __shared__ __align__(16) float vl[N];
    for (int j = threadIdx.x; j < N / 4; j += 256)
        ((float4*)vl)[j] = ((const float4*)v)[j];
    __syncthreads();
    const int w    = threadIdx.x >> 6;
    const int lane = threadIdx.x & 63;
    const int i    = blockIdx.x * 4 + w;
    const float4* krow = (const float4*)(K + (size_t)i * N);
    const float4* v4   = (const float4*)vl;
    float acc = 0.f;
    for (int c = lane; c < N / 4; c += 64) {
        float4 k  = krow[c];
        float4 vv = v4[c];
        acc += k.x * vv.x + k.y * vv.y + k.z * vv.z + k.w * vv.w;
    }
    for (int off = 32; off > 0; off >>= 1)
        acc += __shfl_down(acc, off, 64);
    if (lane == 0) {
        float un = av[i] / (acc + EPSV);
        float d  = un - u[i];
        du2[i] = d * d;
        u[i]   = un;
    }
}

__global__ __launch_bounds__(256)
void k_err(const float* __restrict__ du2, int* __restrict__ flag)
{
    if (*flag) return;
    __shared__ float r[4];
    float s = 0.f;
    for (int i = threadIdx.x; i < N; i += 256) s += du2[i];
    for (int off = 32; off > 0; off >>= 1)
        s += __shfl_down(s, off, 64);
    if ((threadIdx.x & 63) == 0) r[threadIdx.x >> 6] = s;
    __syncthreads();
    if (threadIdx.x == 0) {
        float e = sqrtf(r[0] + r[1] + r[2] + r[3]);
        if (e < THRESH) *flag = 1;
    }
}

__global__ __launch_bounds__(256)
void k_final(float* __restrict__ K, const float* __restrict__ u,
             const float* __restrict__ v)
{
    __shared__ __align__(16) float vl[N];
    for (int j = threadIdx.x; j < N / 4; j += 256)
        ((float4*)vl)[j] = ((const float4*)v)[j];
    __syncthreads();
    const int w    = threadIdx.x >> 6;
    const int lane = threadIdx.x & 63;
    const int i    = blockIdx.x * 4 + w;
    const float ui = u[i];
    float4* krow = (float4*)(K + (size_t)i * N);
    const float4* v4 = (const float4*)vl;
    for (int c = lane; c < N / 4; c += 64) {
        float4 k  = krow[c];
        float4 vv = v4[c];
        k.x *= ui * vv.x; k.y *= ui * vv.y; k.z *= ui * vv.z; k.w *= ui * vv.w;
        krow[c] = k;
    }
}

// ===========================================================================
extern "C" void kernel_launch(void* const* d_in, const int* in_sizes, int n_in,
                              void* d_out, int out_size, void* d_ws, size_t ws_size,
                              hipStream_t stream)
{
    const float* cost = (const float*)d_in[0];
    const float* av   = (const float*)d_in[1];
    const float* bv   = (const float*)d_in[2];
    float* out = (float*)d_out;

    // ws layout: u32[N] | v32[N] | bsum[256] | bar(64B slot) | u16[N] | v16[N] | K8 | KT8
    float*        u32  = (float*)d_ws;
    float*        v32  = u32 + N;
    float*        bsum = v32 + N;
    unsigned int* bar  = (unsigned int*)(bsum + 256);
    __half*       u16  = (__half*)(bar + 16);
    __half*       v16  = u16 + N;
    unsigned char* base = (unsigned char*)(v16 + N);
    const size_t  head  = (size_t)((unsigned char*)base - (unsigned char*)d_ws);
    const size_t  szK8  = (size_t)N * N;
    const size_t  need8 = head + 2 * szK8;    // ~128 MB

    if (ws_size >= need8) {
        unsigned char* K8  = base;
        unsigned char* KT8 = base + szK8;
        k_init8<<<dim3(64, 64), NTHR, 0, stream>>>(cost, K8, KT8, u32, u16, bar);
        sinkhorn_loop8<<<LBLK, LTHR, 0, stream>>>(av, bv, u32, v32, u16, v16,
                                                  bsum, bar, K8, KT8);
        k_output<<<2048, NTHR, 0, stream>>>(cost, u32, v32, out);
        return;
    }

    // ---- tier 3: proven multi-kernel fp32 path ----
    int*   flag    = (int*)d_ws;
    float* uf      = (float*)d_ws + 16;
    float* vf      = uf + N;
    float* du2f    = vf + N;
    float* partial = du2f + N;

    k_init<<<2048, 256, 0, stream>>>(cost, out, uf, flag);
    for (int it = 0; it < MAX_IT; ++it) {
        k_colmv<<<1024, 256, 0, stream>>>(out, uf, partial, flag);
        k_v    <<<  32, 256, 0, stream>>>(partial, bv, vf, flag);
        k_rowmv<<<2048, 256, 0, stream>>>(out, av, vf, uf, du2f, flag);
        k_err  <<<   1, 256, 0, stream>>>(du2f, flag);
    }
    k_final<<<2048, 256, 0, stream>>>(out, uf, vf);
}